// Round 11
// baseline (144.224 us; speedup 1.0000x reference)
//
#include <hip/hip_runtime.h>

#define CHN 96
#define IMG_H 256
#define IMG_W 256
#define STRIP 32          // rows per wave: 12288 waves (R8's winning grain)
#define WPB 4             // waves per block (256 threads), 3072 blocks
#define GRP 8             // rows per group (R8's winning depth)

typedef float vfloat4 __attribute__((ext_vector_type(4)));

__device__ __forceinline__ vfloat4 ldrow(const float* xp, int yy, int col) {
    // yy >= 0 guaranteed by callers; zero-fill past the bottom edge.
    if (yy < IMG_H)
        return __builtin_nontemporal_load(
            (const vfloat4*)(xp + (size_t)yy * IMG_W + col));
    return (vfloat4){0.f, 0.f, 0.f, 0.f};
}

__device__ __forceinline__ void ldgroup(vfloat4* buf, const float* xp,
                                        int y0, int col) {
    #pragma unroll
    for (int j = 0; j < GRP; ++j) buf[j] = ldrow(xp, y0 + j, col);
}

// Horizontal 3-tap sum for the lane's 4 pixels (zero pad at x=-1 / x=256).
__device__ __forceinline__ vfloat4 hsum3(vfloat4 v, int lane) {
    float l = __shfl_up(v.w, 1);
    float r = __shfl_down(v.x, 1);
    if (lane == 0)  l = 0.f;
    if (lane == 63) r = 0.f;
    float t1 = v.x + v.y;
    float t2 = v.z + v.w;
    vfloat4 h;
    h.x = l   + t1;
    h.y = t1  + v.z;
    h.z = v.y + t2;
    h.w = t2  + r;
    return h;
}

__device__ __forceinline__ void compute_group(const vfloat4* buf,
                                              vfloat4& hprev, vfloat4& hcur,
                                              vfloat4& ccur,
                                              float wn, float wd,
                                              float* op, int y, int col, int lane) {
    #pragma unroll
    for (int j = 0; j < GRP; ++j) {
        vfloat4 hn = hsum3(buf[j], lane);     // input row y+j+1
        vfloat4 s  = hprev + hcur + hn;       // 3x3 box sum
        vfloat4 o  = s * wn + ccur * wd;
        __builtin_nontemporal_store(
            o, (vfloat4*)(op + (size_t)(y + j) * IMG_W + col));
        hprev = hcur;
        hcur  = hn;
        ccur  = buf[j];
    }
}

// R8 structure with the drain-copy replaced by straight-line ping-pong:
// no va[]=vb[] copies -> no s_waitcnt vmcnt(0) at group boundaries; the
// next group's 8 loads stay in flight while the current group computes.
__global__ __launch_bounds__(WPB * 64)
void sharpen3x3_pp2(const float* __restrict__ x,
                    const float* __restrict__ kern,
                    float* __restrict__ out)
{
    const int lane = threadIdx.x & 63;
    const int wave = threadIdx.x >> 6;

    const int strip_id = blockIdx.x * WPB + wave;            // 0..12287
    const int spp      = IMG_H / STRIP;                      // 8 strips per plane
    const int plane    = strip_id / spp;                     // n*CHN + c
    const int sy       = (strip_id % spp) * STRIP;           // first output row
    const int c        = plane % CHN;

    // Diagonal 3x3 block of the dense (C,C,3,3) kernel; sharpen has one
    // neighbor weight kw[0] and one center weight kw[4]:
    //   out = wn * box3x3_sum + (w_center - wn) * center
    const float* kw = kern + ((size_t)c * CHN + c) * 9;
    const float wn = kw[0];
    const float wd = kw[4] - wn;

    const float* xp = x   + (size_t)plane * IMG_H * IMG_W;
    float*       op = out + (size_t)plane * IMG_H * IMG_W;
    const int col = 4 * lane;

    // ---- prime: issue top rows + group0 + group1 before any use ----
    vfloat4 vtop = (sy == 0) ? (vfloat4){0.f, 0.f, 0.f, 0.f}
                             : *(const vfloat4*)(xp + (size_t)(sy - 1) * IMG_W + col);
    vfloat4 v0   = *(const vfloat4*)(xp + (size_t)sy * IMG_W + col);

    vfloat4 A[GRP], B[GRP];
    ldgroup(A, xp, sy + 1, col);              // inputs for rows sy+0 .. sy+7

    vfloat4 hprev = hsum3(vtop, lane);
    if (sy == 0) hprev = (vfloat4){0.f, 0.f, 0.f, 0.f};
    vfloat4 hcur = hsum3(v0, lane);
    vfloat4 ccur = v0;

    // ---- straight-line ping-pong over 4 groups ----
    ldgroup(B, xp, sy + GRP + 1, col);        // inputs for rows sy+8 .. sy+15
    compute_group(A, hprev, hcur, ccur, wn, wd, op, sy, col, lane);

    ldgroup(A, xp, sy + 2 * GRP + 1, col);    // inputs for rows sy+16 .. sy+23
    compute_group(B, hprev, hcur, ccur, wn, wd, op, sy + GRP, col, lane);

    ldgroup(B, xp, sy + 3 * GRP + 1, col);    // inputs for rows sy+24 .. sy+31
    compute_group(A, hprev, hcur, ccur, wn, wd, op, sy + 2 * GRP, col, lane);

    compute_group(B, hprev, hcur, ccur, wn, wd, op, sy + 3 * GRP, col, lane);
}

extern "C" void kernel_launch(void* const* d_in, const int* in_sizes, int n_in,
                              void* d_out, int out_size, void* d_ws, size_t ws_size,
                              hipStream_t stream) {
    const float* x    = (const float*)d_in[0];
    const float* kern = (const float*)d_in[1];
    float* out        = (float*)d_out;

    const int n_strips = 16 * CHN * (IMG_H / STRIP);   // 12288 waves
    const int grid     = n_strips / WPB;               // 3072 blocks

    hipLaunchKernelGGL(sharpen3x3_pp2, dim3(grid), dim3(WPB * 64),
                       0, stream, x, kern, out);
}